// Round 5
// baseline (565.360 us; speedup 1.0000x reference)
//
#include <hip/hip_runtime.h>
#include <math.h>

#define Bsz 128
#define Nn  512
#define Fd  64
#define Dd  64
#define Kk  20
#define BN  (Bsz*Nn)   // 65536
#define NCPY 16        // replicated stat accumulators (contention control)

__device__ __forceinline__ float leaky(float v){ return (v >= 0.f) ? v : 0.2f*v; }

// bf16 helpers (RNE)
__device__ __forceinline__ unsigned short f2bf(float f){
  unsigned u = __float_as_uint(f);
  return (unsigned short)((u + 0x7FFFu + ((u >> 16) & 1u)) >> 16);
}
__device__ __forceinline__ float bf2f(unsigned short h){
  return __uint_as_float(((unsigned)h) << 16);
}
__device__ __forceinline__ ushort4 pack4(float4 v){
  ushort4 r; r.x = f2bf(v.x); r.y = f2bf(v.y); r.z = f2bf(v.z); r.w = f2bf(v.w);
  return r;
}
__device__ __forceinline__ float4 unpack4(ushort4 v){
  float4 r; r.x = bf2f(v.x); r.y = bf2f(v.y); r.z = bf2f(v.z); r.w = bf2f(v.w);
  return r;
}

// reduce over lanes 0..31 only (lanes 32-63 hold identity values)
__device__ __forceinline__ float wave_max32(float v){
  #pragma unroll
  for (int o = 16; o; o >>= 1) v = fmaxf(v, __shfl_xor(v, o, 64));
  return v;
}
__device__ __forceinline__ float wave_sum32(float v){
  #pragma unroll
  for (int o = 16; o; o >>= 1) v += __shfl_xor(v, o, 64);
  return v;
}

// ================= k_topk: cosine top-K, one wave per row, 128 blocks =================
__global__ __launch_bounds__(256) void k_topk(const float* __restrict__ embed,
                                              int* __restrict__ topk){
  __shared__ __align__(16) float rnorm[Nn];
  __shared__ __align__(16) float se[256];
  int tid = threadIdx.x, bb = blockIdx.x;
  for (int r = tid; r < Nn; r += 256){
    const float4* er = (const float4*)(embed + r*Dd);
    float ss = 0.f;
    #pragma unroll
    for (int q = 0; q < 16; q++){
      float4 e4 = er[q];
      ss += e4.x*e4.x + e4.y*e4.y + e4.z*e4.z + e4.w*e4.w;
    }
    rnorm[r] = 1.f/(sqrtf(ss) + 1e-12f);
  }
  se[tid] = embed[bb*256 + tid];       // this block's 4 query rows
  __syncthreads();
  int wv = tid >> 6, lane = tid & 63;
  int row = bb*4 + wv;
  const float4* sev = (const float4*)(se + wv*64);
  float av[8];
  #pragma unroll
  for (int rep = 0; rep < 8; rep++){
    int c = rep*64 + lane;
    const float4* ej = (const float4*)(embed + c*Dd);
    float s0 = 0.f;
    #pragma unroll
    for (int q = 0; q < 16; q++){
      float4 a = ej[q], b4 = sev[q];
      s0 += a.x*b4.x + a.y*b4.y + a.z*b4.z + a.w*b4.w;
    }
    av[rep] = s0 * rnorm[c];           // query-row norm is argmax-invariant
  }
  #pragma unroll 1
  for (int t = 0; t < Kk; t++){
    float bv = av[0]; int br = 0;
    #pragma unroll
    for (int rep = 1; rep < 8; rep++)
      if (av[rep] > bv){ bv = av[rep]; br = rep; }   // strict > = lowest c per lane
    int ci = br*64 + lane;
    #pragma unroll
    for (int o = 32; o; o >>= 1){
      float ov = __shfl_xor(bv, o, 64);
      int   oi = __shfl_xor(ci, o, 64);
      if (ov > bv || (ov == bv && oi < ci)){ bv = ov; ci = oi; }
    }
    if (lane == 0) topk[row*Kk + t] = ci;
    int wr = ci >> 6;
    if ((ci & 63) == lane){
      #pragma unroll
      for (int rep = 0; rep < 8; rep++)
        if (rep == wr) av[rep] = -INFINITY;
    }
  }
}

// ================= k_lin: g = x@W (bf16 out) + attention scores =================
__global__ __launch_bounds__(256, 4) void k_lin(const float* __restrict__ x,
    const float* __restrict__ W, const float* __restrict__ embed,
    const float* __restrict__ att_i, const float* __restrict__ att_j,
    const float* __restrict__ aem_i, const float* __restrict__ aem_j,
    unsigned short* __restrict__ g, float* __restrict__ s_i, float* __restrict__ s_j){
  __shared__ __align__(16) float4 sW[Fd*16];          // 16 KB
  __shared__ __align__(16) float4 sai[16], saj[16], semi[16], semj[16];
  int tid = threadIdx.x, b = blockIdx.x;
  const float4* W4 = (const float4*)W;
  #pragma unroll
  for (int t = 0; t < 4; t++) sW[tid + 256*t] = W4[tid + 256*t];
  if (tid < 16){
    sai[tid]  = ((const float4*)att_i)[tid];
    saj[tid]  = ((const float4*)att_j)[tid];
    semi[tid] = ((const float4*)aem_i)[tid];
    semj[tid] = ((const float4*)aem_j)[tid];
  }
  __syncthreads();
  int rowgrp = tid >> 4, cg = tid & 15;
  int row0 = b*64 + rowgrp*4;
  float4 acc0={0,0,0,0}, acc1={0,0,0,0}, acc2={0,0,0,0}, acc3={0,0,0,0};
  const float4* xr0 = (const float4*)(x + (row0+0)*Fd);
  const float4* xr1 = (const float4*)(x + (row0+1)*Fd);
  const float4* xr2 = (const float4*)(x + (row0+2)*Fd);
  const float4* xr3 = (const float4*)(x + (row0+3)*Fd);
  #pragma unroll
  for (int qk = 0; qk < 16; qk++){
    float4 x0 = xr0[qk], x1 = xr1[qk], x2 = xr2[qk], x3 = xr3[qk];
    float xs0[4] = {x0.x,x0.y,x0.z,x0.w};
    float xs1[4] = {x1.x,x1.y,x1.z,x1.w};
    float xs2[4] = {x2.x,x2.y,x2.z,x2.w};
    float xs3[4] = {x3.x,x3.y,x3.z,x3.w};
    #pragma unroll
    for (int s = 0; s < 4; s++){
      float4 w4 = sW[(4*qk + s)*16 + cg];
      acc0.x += xs0[s]*w4.x; acc0.y += xs0[s]*w4.y; acc0.z += xs0[s]*w4.z; acc0.w += xs0[s]*w4.w;
      acc1.x += xs1[s]*w4.x; acc1.y += xs1[s]*w4.y; acc1.z += xs1[s]*w4.z; acc1.w += xs1[s]*w4.w;
      acc2.x += xs2[s]*w4.x; acc2.y += xs2[s]*w4.y; acc2.z += xs2[s]*w4.z; acc2.w += xs2[s]*w4.w;
      acc3.x += xs3[s]*w4.x; acc3.y += xs3[s]*w4.y; acc3.z += xs3[s]*w4.z; acc3.w += xs3[s]*w4.w;
    }
  }
  float4 ai = sai[cg], aj = saj[cg], emi = semi[cg], emj = semj[cg];
  float4 avv[4] = {acc0, acc1, acc2, acc3};
  #pragma unroll
  for (int r = 0; r < 4; r++){
    int row = row0 + r;
    int node = row & (Nn-1);
    float4 a4 = avv[r];
    float4 e4 = ((const float4*)embed)[node*16 + cg];
    float si = a4.x*ai.x + a4.y*ai.y + a4.z*ai.z + a4.w*ai.w
             + e4.x*emi.x + e4.y*emi.y + e4.z*emi.z + e4.w*emi.w;
    float sj = a4.x*aj.x + a4.y*aj.y + a4.z*aj.z + a4.w*aj.w
             + e4.x*emj.x + e4.y*emj.y + e4.z*emj.z + e4.w*emj.w;
    #pragma unroll
    for (int o = 1; o < 16; o <<= 1){
      si += __shfl_xor(si, o, 64);
      sj += __shfl_xor(sj, o, 64);
    }
    if (cg == 0){ s_i[row] = si; s_j[row] = sj; }
    ((ushort4*)g)[row*16 + cg] = pack4(a4);     // bf16 g
  }
}

// ================= k2: softmax + gather-aggregate (bf16 g/agg) + BN1 stats =================
__global__ __launch_bounds__(256) void k2(const unsigned short* __restrict__ g,
    const float* __restrict__ s_i, const float* __restrict__ s_j,
    const int* __restrict__ topk, const float* __restrict__ bias,
    unsigned short* __restrict__ agg, float* __restrict__ stats){
  __shared__ float  swt[4][4][24];
  __shared__ int    sji[4][4][24];
  __shared__ float4 sred_s[4][16], sred_q[4][16];
  __shared__ float4 sbias[16];
  int tid = threadIdx.x, wv = tid >> 6, lane = tid & 63;
  if (tid < 16) sbias[tid] = ((const float4*)bias)[tid];
  __syncthreads();
  // bid%8 preserved -> each batch's g-slab stays on one XCD's L2
  int bid = blockIdx.x;
  int xcd = bid & 7, q = bid >> 3;             // q 0..63
  int batch = xcd*16 + (q & 15);
  int quarter = q >> 4;                        // 0..3
  int base = batch*Nn;
  int node0 = quarter*128 + wv*32;
  const ushort4* g4 = (const ushort4*)g;
  int h = lane >> 4, c = lane & 15;
  float4 s4 = {0,0,0,0}, q4 = {0,0,0,0};
  #pragma unroll 1
  for (int gI = 0; gI < 8; gI++){
    #pragma unroll
    for (int h4 = 0; h4 < 4; h4++){
      int node = node0 + gI*4 + h4;
      int dest = base + node;
      float si_d = s_i[dest];
      float lg = -INFINITY; int j = node;
      if (lane < Kk){
        j = topk[node*Kk + lane];
        if (j != node) lg = leaky(si_d + s_j[base + j]);  // self in topk masked
      } else if (lane == Kk){
        lg = leaky(si_d + s_j[dest]);                     // appended self loop
      }
      // lanes 32-63 hold identity values; only lanes<24 consume the result
      float m  = wave_max32(lg);
      float e_ = (lane <= Kk) ? __expf(lg - m) : 0.f;     // one exp per edge lane
      float denom = wave_sum32(e_);
      if (lane < 24){
        swt[wv][h4][lane] = (lane <= Kk) ? e_/denom : 0.f;
        sji[wv][h4][lane] = j;
      }
    }
    float la[24]; int ja[24];                 // wave-synchronous LDS readback
    const float4* lv = (const float4*)swt[wv][h];
    const int4*   jv = (const int4*)sji[wv][h];
    #pragma unroll
    for (int qq = 0; qq < 6; qq++){
      float4 f = lv[qq]; la[4*qq]=f.x; la[4*qq+1]=f.y; la[4*qq+2]=f.z; la[4*qq+3]=f.w;
      int4  ii = jv[qq]; ja[4*qq]=ii.x; ja[4*qq+1]=ii.y; ja[4*qq+2]=ii.z; ja[4*qq+3]=ii.w;
    }
    float4 acc = sbias[c];
    #pragma unroll
    for (int e = 0; e <= Kk; e++){
      float4 gv = unpack4(g4[(base + ja[e])*16 + c]);  // bf16 gather, 4 dests/round
      acc.x += la[e]*gv.x; acc.y += la[e]*gv.y; acc.z += la[e]*gv.z; acc.w += la[e]*gv.w;
    }
    int dest = base + node0 + gI*4 + h;
    ((ushort4*)agg)[dest*16 + c] = pack4(acc);         // bf16 agg
    s4.x += acc.x; s4.y += acc.y; s4.z += acc.z; s4.w += acc.w;   // fp32 stats
    q4.x += acc.x*acc.x; q4.y += acc.y*acc.y; q4.z += acc.z*acc.z; q4.w += acc.w*acc.w;
  }
  #pragma unroll
  for (int o = 16; o <= 32; o <<= 1){
    s4.x += __shfl_xor(s4.x,o,64); s4.y += __shfl_xor(s4.y,o,64);
    s4.z += __shfl_xor(s4.z,o,64); s4.w += __shfl_xor(s4.w,o,64);
    q4.x += __shfl_xor(q4.x,o,64); q4.y += __shfl_xor(q4.y,o,64);
    q4.z += __shfl_xor(q4.z,o,64); q4.w += __shfl_xor(q4.w,o,64);
  }
  if (lane < 16){ sred_s[wv][lane] = s4; sred_q[wv][lane] = q4; }
  __syncthreads();
  float* sc = stats + (bid & (NCPY-1))*256;   // replicated accumulators
  if (wv == 0 && lane < 16){
    float4 a = sred_s[0][lane];
    #pragma unroll
    for (int w = 1; w < 4; w++){ float4 t = sred_s[w][lane]; a.x+=t.x; a.y+=t.y; a.z+=t.z; a.w+=t.w; }
    atomicAdd(&sc[lane*4+0], a.x); atomicAdd(&sc[lane*4+1], a.y);
    atomicAdd(&sc[lane*4+2], a.z); atomicAdd(&sc[lane*4+3], a.w);
  }
  if (wv == 1 && lane < 16){
    float4 a = sred_q[0][lane];
    #pragma unroll
    for (int w = 1; w < 4; w++){ float4 t = sred_q[w][lane]; a.x+=t.x; a.y+=t.y; a.z+=t.z; a.w+=t.w; }
    atomicAdd(&sc[64+lane*4+0], a.x); atomicAdd(&sc[64+lane*4+1], a.y);
    atomicAdd(&sc[64+lane*4+2], a.z); atomicAdd(&sc[64+lane*4+3], a.w);
  }
}

// ================= k3: (inline BN1 finalize) + recompute h2 + BN2 stats =================
__global__ __launch_bounds__(256) void k3(const unsigned short* __restrict__ agg,
    const float* __restrict__ embed, const float* __restrict__ bn1g,
    const float* __restrict__ bn1b, float* __restrict__ stats){
  __shared__ float ssc[64], ssh[64];
  __shared__ float4 sred_s[4][16], sred_q[4][16];
  int tid = threadIdx.x;
  if (tid < 64){
    float s = 0.f, qq = 0.f;
    #pragma unroll
    for (int x = 0; x < NCPY; x++){ s += stats[x*256 + tid]; qq += stats[x*256 + 64 + tid]; }
    float mu = s*(1.f/BN), var = qq*(1.f/BN) - mu*mu;
    float sc = bn1g[tid]/sqrtf(var + 1e-5f);
    ssc[tid] = sc; ssh[tid] = bn1b[tid] - mu*sc;
  }
  __syncthreads();
  int gt = blockIdx.x*256 + tid;
  int c = gt & 15, r0 = gt >> 4;               // 4096-row stride keeps node const
  int wv = tid >> 6, lane = tid & 63;
  float4 sc1 = ((const float4*)ssc)[c], sh1 = ((const float4*)ssh)[c];
  float4 e4 = ((const float4*)embed)[(r0 & (Nn-1))*16 + c];
  float4 s4 = {0,0,0,0}, q4 = {0,0,0,0};
  const ushort4* a4 = (const ushort4*)agg;
  for (int r = r0; r < BN; r += 4096){
    float4 v = unpack4(a4[r*16 + c]);
    v.x = fmaxf(v.x*sc1.x+sh1.x, 0.f)*e4.x;
    v.y = fmaxf(v.y*sc1.y+sh1.y, 0.f)*e4.y;
    v.z = fmaxf(v.z*sc1.z+sh1.z, 0.f)*e4.z;
    v.w = fmaxf(v.w*sc1.w+sh1.w, 0.f)*e4.w;
    s4.x += v.x; s4.y += v.y; s4.z += v.z; s4.w += v.w;
    q4.x += v.x*v.x; q4.y += v.y*v.y; q4.z += v.z*v.z; q4.w += v.w*v.w;
  }
  #pragma unroll
  for (int o = 16; o <= 32; o <<= 1){
    s4.x += __shfl_xor(s4.x,o,64); s4.y += __shfl_xor(s4.y,o,64);
    s4.z += __shfl_xor(s4.z,o,64); s4.w += __shfl_xor(s4.w,o,64);
    q4.x += __shfl_xor(q4.x,o,64); q4.y += __shfl_xor(q4.y,o,64);
    q4.z += __shfl_xor(q4.z,o,64); q4.w += __shfl_xor(q4.w,o,64);
  }
  if (lane < 16){ sred_s[wv][lane] = s4; sred_q[wv][lane] = q4; }
  __syncthreads();
  float* sc = stats + (blockIdx.x & (NCPY-1))*256;
  if (wv == 0 && lane < 16){
    float4 a = sred_s[0][lane];
    #pragma unroll
    for (int w = 1; w < 4; w++){ float4 t = sred_s[w][lane]; a.x+=t.x; a.y+=t.y; a.z+=t.z; a.w+=t.w; }
    atomicAdd(&sc[128+lane*4+0], a.x); atomicAdd(&sc[128+lane*4+1], a.y);
    atomicAdd(&sc[128+lane*4+2], a.z); atomicAdd(&sc[128+lane*4+3], a.w);
  }
  if (wv == 1 && lane < 16){
    float4 a = sred_q[0][lane];
    #pragma unroll
    for (int w = 1; w < 4; w++){ float4 t = sred_q[w][lane]; a.x+=t.x; a.y+=t.y; a.z+=t.z; a.w+=t.w; }
    atomicAdd(&sc[192+lane*4+0], a.x); atomicAdd(&sc[192+lane*4+1], a.y);
    atomicAdd(&sc[192+lane*4+2], a.z); atomicAdd(&sc[192+lane*4+3], a.w);
  }
}

// ================= k4: (inline BN finalize x2) + recompute + output head =================
__global__ __launch_bounds__(256) void k4(const unsigned short* __restrict__ agg,
    const float* __restrict__ embed, const float* __restrict__ bn1g,
    const float* __restrict__ bn1b, const float* __restrict__ bn2g,
    const float* __restrict__ bn2b, const float* __restrict__ outW,
    const float* __restrict__ outb, const float* __restrict__ stats,
    float* __restrict__ out){
  __shared__ float ssc1[64], ssh1[64], ssc2[64], ssh2[64];
  int tid = threadIdx.x;
  if (tid < 64){
    float s1=0.f, q1=0.f, s2=0.f, q2=0.f;
    #pragma unroll
    for (int x = 0; x < NCPY; x++){
      const float* p = stats + x*256;
      s1 += p[tid]; q1 += p[64+tid]; s2 += p[128+tid]; q2 += p[192+tid];
    }
    float mu1 = s1*(1.f/BN), var1 = q1*(1.f/BN) - mu1*mu1;
    float sc1 = bn1g[tid]/sqrtf(var1 + 1e-5f);
    ssc1[tid] = sc1; ssh1[tid] = bn1b[tid] - mu1*sc1;
    float mu2 = s2*(1.f/BN), var2 = q2*(1.f/BN) - mu2*mu2;
    float sc2 = bn2g[tid]/sqrtf(var2 + 1e-5f);
    ssc2[tid] = sc2; ssh2[tid] = bn2b[tid] - mu2*sc2;
  }
  __syncthreads();
  int gt = blockIdx.x*256 + tid;
  int c = gt & 15, r0 = gt >> 4;
  float4 sc1 = ((const float4*)ssc1)[c], sh1 = ((const float4*)ssh1)[c];
  float4 sc2 = ((const float4*)ssc2)[c], sh2 = ((const float4*)ssh2)[c];
  float4 ow  = ((const float4*)outW)[c];
  float ob = outb[0];
  float4 e4 = ((const float4*)embed)[(r0 & (Nn-1))*16 + c];
  const ushort4* a4 = (const ushort4*)agg;
  for (int r = r0; r < BN; r += 4096){
    float4 v = unpack4(a4[r*16 + c]);
    v.x = fmaxf(v.x*sc1.x+sh1.x, 0.f)*e4.x;
    v.y = fmaxf(v.y*sc1.y+sh1.y, 0.f)*e4.y;
    v.z = fmaxf(v.z*sc1.z+sh1.z, 0.f)*e4.z;
    v.w = fmaxf(v.w*sc1.w+sh1.w, 0.f)*e4.w;
    float t = fmaxf(v.x*sc2.x+sh2.x, 0.f)*ow.x
            + fmaxf(v.y*sc2.y+sh2.y, 0.f)*ow.y
            + fmaxf(v.z*sc2.z+sh2.z, 0.f)*ow.z
            + fmaxf(v.w*sc2.w+sh2.w, 0.f)*ow.w;
    #pragma unroll
    for (int o = 1; o < 16; o <<= 1) t += __shfl_xor(t, o, 64);
    if (c == 0) out[r] = t + ob;
  }
}

extern "C" void kernel_launch(void* const* d_in, const int* in_sizes, int n_in,
                              void* d_out, int out_size, void* d_ws, size_t ws_size,
                              hipStream_t stream){
  const float* data  = (const float*)d_in[0];
  // d_in[1] = org_edge_index — unused by the reference computation
  const float* embed = (const float*)d_in[2];
  const float* W_lin = (const float*)d_in[3];
  const float* att_i = (const float*)d_in[4];
  const float* att_j = (const float*)d_in[5];
  const float* aem_i = (const float*)d_in[6];
  const float* aem_j = (const float*)d_in[7];
  const float* bias  = (const float*)d_in[8];
  const float* g1    = (const float*)d_in[9];
  const float* b1    = (const float*)d_in[10];
  const float* g2    = (const float*)d_in[11];
  const float* b2    = (const float*)d_in[12];
  const float* outW  = (const float*)d_in[13];
  const float* outb  = (const float*)d_in[14];
  float* out = (float*)d_out;

  float* ws = (float*)d_ws;
  unsigned short* g   = (unsigned short*)ws;              // 8 MB bf16
  unsigned short* agg = (unsigned short*)(ws + 2097152);  // 8 MB bf16
  float* s_i   = ws + 4194304;             // 65,536
  float* s_j   = s_i + 65536;              // 65,536
  int*   topk  = (int*)(s_j + 65536);      // 10,240
  float* stats = (float*)(topk + Nn*Kk);   // NCPY x 256 f32

  hipMemsetAsync(stats, 0, NCPY*256*sizeof(float), stream);
  k_topk<<<128, 256, 0, stream>>>(embed, topk);
  k_lin <<<1024, 256, 0, stream>>>(data, W_lin, embed, att_i, att_j, aem_i, aem_j,
                                   g, s_i, s_j);
  k2<<<512, 256, 0, stream>>>(g, s_i, s_j, topk, bias, agg, stats);
  k3<<<256, 256, 0, stream>>>(agg, embed, g1, b1, stats);
  k4<<<256, 256, 0, stream>>>(agg, embed, g1, b1, g2, b2, outW, outb, stats, out);
}

// Round 7
// 251.228 us; speedup vs baseline: 2.2504x; 2.2504x over previous
//
#include <hip/hip_runtime.h>
#include <math.h>

#define Bsz 128
#define Nn  512
#define Fd  64
#define Dd  64
#define Kk  20
#define BN  (Bsz*Nn)   // 65536

__device__ __forceinline__ float leaky(float v){ return (v >= 0.f) ? v : 0.2f*v; }

// bf16 helpers (RNE)
__device__ __forceinline__ unsigned short f2bf(float f){
  unsigned u = __float_as_uint(f);
  return (unsigned short)((u + 0x7FFFu + ((u >> 16) & 1u)) >> 16);
}
__device__ __forceinline__ float bf2f(unsigned short h){
  return __uint_as_float(((unsigned)h) << 16);
}
__device__ __forceinline__ ushort4 pack4(float4 v){
  ushort4 r; r.x = f2bf(v.x); r.y = f2bf(v.y); r.z = f2bf(v.z); r.w = f2bf(v.w);
  return r;
}
__device__ __forceinline__ float4 unpack4(ushort4 v){
  float4 r; r.x = bf2f(v.x); r.y = bf2f(v.y); r.z = bf2f(v.z); r.w = bf2f(v.w);
  return r;
}

// reduce over lanes 0..31 only (lanes 32-63 hold identity values)
__device__ __forceinline__ float wave_max32(float v){
  #pragma unroll
  for (int o = 16; o; o >>= 1) v = fmaxf(v, __shfl_xor(v, o, 64));
  return v;
}
__device__ __forceinline__ float wave_sum32(float v){
  #pragma unroll
  for (int o = 16; o; o >>= 1) v += __shfl_xor(v, o, 64);
  return v;
}

// ================= k_topk: cosine top-K, one wave per row, 128 blocks =================
__global__ __launch_bounds__(256) void k_topk(const float* __restrict__ embed,
                                              int* __restrict__ topk){
  __shared__ __align__(16) float rnorm[Nn];
  __shared__ __align__(16) float se[256];
  int tid = threadIdx.x, bb = blockIdx.x;
  for (int r = tid; r < Nn; r += 256){
    const float4* er = (const float4*)(embed + r*Dd);
    float ss = 0.f;
    #pragma unroll
    for (int q = 0; q < 16; q++){
      float4 e4 = er[q];
      ss += e4.x*e4.x + e4.y*e4.y + e4.z*e4.z + e4.w*e4.w;
    }
    rnorm[r] = 1.f/(sqrtf(ss) + 1e-12f);
  }
  se[tid] = embed[bb*256 + tid];       // this block's 4 query rows
  __syncthreads();
  int wv = tid >> 6, lane = tid & 63;
  int row = bb*4 + wv;
  const float4* sev = (const float4*)(se + wv*64);
  float av[8];
  #pragma unroll
  for (int rep = 0; rep < 8; rep++){
    int c = rep*64 + lane;
    const float4* ej = (const float4*)(embed + c*Dd);
    float s0 = 0.f;
    #pragma unroll
    for (int q = 0; q < 16; q++){
      float4 a = ej[q], b4 = sev[q];
      s0 += a.x*b4.x + a.y*b4.y + a.z*b4.z + a.w*b4.w;
    }
    av[rep] = s0 * rnorm[c];           // query-row norm is argmax-invariant
  }
  #pragma unroll 1
  for (int t = 0; t < Kk; t++){
    float bv = av[0]; int br = 0;
    #pragma unroll
    for (int rep = 1; rep < 8; rep++)
      if (av[rep] > bv){ bv = av[rep]; br = rep; }   // strict > = lowest c per lane
    int ci = br*64 + lane;
    #pragma unroll
    for (int o = 32; o; o >>= 1){
      float ov = __shfl_xor(bv, o, 64);
      int   oi = __shfl_xor(ci, o, 64);
      if (ov > bv || (ov == bv && oi < ci)){ bv = ov; ci = oi; }
    }
    if (lane == 0) topk[row*Kk + t] = ci;
    int wr = ci >> 6;
    if ((ci & 63) == lane){
      #pragma unroll
      for (int rep = 0; rep < 8; rep++)
        if (rep == wr) av[rep] = -INFINITY;
    }
  }
}

// ================= k_lin: g = x@W (bf16 out) + attention scores =================
// NOTE: no min-waves floor in launch_bounds and NO full unroll of the qk loop —
// __launch_bounds__(256,4) capped VGPR at 64 and spilled the accumulators to
// scratch: 1 GB of HBM traffic, 392 us (round 5). VGPR ~100, zero spill, is right.
__global__ __launch_bounds__(256) void k_lin(const float* __restrict__ x,
    const float* __restrict__ W, const float* __restrict__ embed,
    const float* __restrict__ att_i, const float* __restrict__ att_j,
    const float* __restrict__ aem_i, const float* __restrict__ aem_j,
    unsigned short* __restrict__ g, float* __restrict__ s_i, float* __restrict__ s_j){
  __shared__ __align__(16) float4 sW[Fd*16];          // 16 KB
  __shared__ __align__(16) float4 sai[16], saj[16], semi[16], semj[16];
  int tid = threadIdx.x, b = blockIdx.x;
  const float4* W4 = (const float4*)W;
  #pragma unroll
  for (int t = 0; t < 4; t++) sW[tid + 256*t] = W4[tid + 256*t];
  if (tid < 16){
    sai[tid]  = ((const float4*)att_i)[tid];
    saj[tid]  = ((const float4*)att_j)[tid];
    semi[tid] = ((const float4*)aem_i)[tid];
    semj[tid] = ((const float4*)aem_j)[tid];
  }
  __syncthreads();
  int rowgrp = tid >> 4, cg = tid & 15;
  int row0 = b*64 + rowgrp*4;
  float4 acc0={0,0,0,0}, acc1={0,0,0,0}, acc2={0,0,0,0}, acc3={0,0,0,0};
  const float4* xr0 = (const float4*)(x + (row0+0)*Fd);
  const float4* xr1 = (const float4*)(x + (row0+1)*Fd);
  const float4* xr2 = (const float4*)(x + (row0+2)*Fd);
  const float4* xr3 = (const float4*)(x + (row0+3)*Fd);
  for (int qk = 0; qk < 16; qk++){
    float4 x0 = xr0[qk], x1 = xr1[qk], x2 = xr2[qk], x3 = xr3[qk];
    float xs0[4] = {x0.x,x0.y,x0.z,x0.w};
    float xs1[4] = {x1.x,x1.y,x1.z,x1.w};
    float xs2[4] = {x2.x,x2.y,x2.z,x2.w};
    float xs3[4] = {x3.x,x3.y,x3.z,x3.w};
    #pragma unroll
    for (int s = 0; s < 4; s++){
      float4 w4 = sW[(4*qk + s)*16 + cg];
      acc0.x += xs0[s]*w4.x; acc0.y += xs0[s]*w4.y; acc0.z += xs0[s]*w4.z; acc0.w += xs0[s]*w4.w;
      acc1.x += xs1[s]*w4.x; acc1.y += xs1[s]*w4.y; acc1.z += xs1[s]*w4.z; acc1.w += xs1[s]*w4.w;
      acc2.x += xs2[s]*w4.x; acc2.y += xs2[s]*w4.y; acc2.z += xs2[s]*w4.z; acc2.w += xs2[s]*w4.w;
      acc3.x += xs3[s]*w4.x; acc3.y += xs3[s]*w4.y; acc3.z += xs3[s]*w4.z; acc3.w += xs3[s]*w4.w;
    }
  }
  float4 ai = sai[cg], aj = saj[cg], emi = semi[cg], emj = semj[cg];
  float4 avv[4] = {acc0, acc1, acc2, acc3};
  #pragma unroll
  for (int r = 0; r < 4; r++){
    int row = row0 + r;
    int node = row & (Nn-1);
    float4 a4 = avv[r];
    float4 e4 = ((const float4*)embed)[node*16 + cg];
    float si = a4.x*ai.x + a4.y*ai.y + a4.z*ai.z + a4.w*ai.w
             + e4.x*emi.x + e4.y*emi.y + e4.z*emi.z + e4.w*emi.w;
    float sj = a4.x*aj.x + a4.y*aj.y + a4.z*aj.z + a4.w*aj.w
             + e4.x*emj.x + e4.y*emj.y + e4.z*emj.z + e4.w*emj.w;
    #pragma unroll
    for (int o = 1; o < 16; o <<= 1){
      si += __shfl_xor(si, o, 64);
      sj += __shfl_xor(sj, o, 64);
    }
    if (cg == 0){ s_i[row] = si; s_j[row] = sj; }
    ((ushort4*)g)[row*16 + cg] = pack4(a4);     // bf16 g
  }
}

// ================= k2: softmax + gather-aggregate (bf16) + per-block BN1 partials ==========
// NO atomics / NO memset: each block owns part1[bid*128 .. +128) — deterministic
// under graph replay (round 6 post-timing tripwire traced to memset+atomic stats).
__global__ __launch_bounds__(256) void k2(const unsigned short* __restrict__ g,
    const float* __restrict__ s_i, const float* __restrict__ s_j,
    const int* __restrict__ topk, const float* __restrict__ bias,
    unsigned short* __restrict__ agg, float* __restrict__ part1){
  __shared__ float  swt[4][4][24];
  __shared__ int    sji[4][4][24];
  __shared__ float4 sred_s[4][16], sred_q[4][16];
  __shared__ float4 sbias[16];
  int tid = threadIdx.x, wv = tid >> 6, lane = tid & 63;
  if (tid < 16) sbias[tid] = ((const float4*)bias)[tid];
  __syncthreads();
  // bid%8 preserved -> each batch's g-slab stays on one XCD's L2
  int bid = blockIdx.x;
  int xcd = bid & 7, q = bid >> 3;             // q 0..63
  int batch = xcd*16 + (q & 15);
  int quarter = q >> 4;                        // 0..3
  int base = batch*Nn;
  int node0 = quarter*128 + wv*32;
  const ushort4* g4 = (const ushort4*)g;
  int h = lane >> 4, c = lane & 15;
  float4 s4 = {0,0,0,0}, q4 = {0,0,0,0};
  #pragma unroll 1
  for (int gI = 0; gI < 8; gI++){
    #pragma unroll
    for (int h4 = 0; h4 < 4; h4++){
      int node = node0 + gI*4 + h4;
      int dest = base + node;
      float si_d = s_i[dest];
      float lg = -INFINITY; int j = node;
      if (lane < Kk){
        j = topk[node*Kk + lane];
        if (j != node) lg = leaky(si_d + s_j[base + j]);  // self in topk masked
      } else if (lane == Kk){
        lg = leaky(si_d + s_j[dest]);                     // appended self loop
      }
      // lanes 32-63 hold identity values; only lanes<24 consume the result
      float m  = wave_max32(lg);
      float e_ = (lane <= Kk) ? __expf(lg - m) : 0.f;     // one exp per edge lane
      float denom = wave_sum32(e_);
      if (lane < 24){
        swt[wv][h4][lane] = (lane <= Kk) ? e_/denom : 0.f;
        sji[wv][h4][lane] = j;
      }
    }
    float la[24]; int ja[24];                 // wave-synchronous LDS readback
    const float4* lv = (const float4*)swt[wv][h];
    const int4*   jv = (const int4*)sji[wv][h];
    #pragma unroll
    for (int qq = 0; qq < 6; qq++){
      float4 f = lv[qq]; la[4*qq]=f.x; la[4*qq+1]=f.y; la[4*qq+2]=f.z; la[4*qq+3]=f.w;
      int4  ii = jv[qq]; ja[4*qq]=ii.x; ja[4*qq+1]=ii.y; ja[4*qq+2]=ii.z; ja[4*qq+3]=ii.w;
    }
    float4 acc = sbias[c];
    #pragma unroll
    for (int e = 0; e <= Kk; e++){
      float4 gv = unpack4(g4[(base + ja[e])*16 + c]);  // bf16 gather, 4 dests/round
      acc.x += la[e]*gv.x; acc.y += la[e]*gv.y; acc.z += la[e]*gv.z; acc.w += la[e]*gv.w;
    }
    int dest = base + node0 + gI*4 + h;
    ((ushort4*)agg)[dest*16 + c] = pack4(acc);         // bf16 agg
    s4.x += acc.x; s4.y += acc.y; s4.z += acc.z; s4.w += acc.w;   // fp32 stats
    q4.x += acc.x*acc.x; q4.y += acc.y*acc.y; q4.z += acc.z*acc.z; q4.w += acc.w*acc.w;
  }
  #pragma unroll
  for (int o = 16; o <= 32; o <<= 1){
    s4.x += __shfl_xor(s4.x,o,64); s4.y += __shfl_xor(s4.y,o,64);
    s4.z += __shfl_xor(s4.z,o,64); s4.w += __shfl_xor(s4.w,o,64);
    q4.x += __shfl_xor(q4.x,o,64); q4.y += __shfl_xor(q4.y,o,64);
    q4.z += __shfl_xor(q4.z,o,64); q4.w += __shfl_xor(q4.w,o,64);
  }
  if (lane < 16){ sred_s[wv][lane] = s4; sred_q[wv][lane] = q4; }
  __syncthreads();
  float* p = part1 + bid*128;
  if (wv == 0 && lane < 16){
    float4 a = sred_s[0][lane];
    #pragma unroll
    for (int w = 1; w < 4; w++){ float4 t = sred_s[w][lane]; a.x+=t.x; a.y+=t.y; a.z+=t.z; a.w+=t.w; }
    ((float4*)p)[lane] = a;
  }
  if (wv == 1 && lane < 16){
    float4 a = sred_q[0][lane];
    #pragma unroll
    for (int w = 1; w < 4; w++){ float4 t = sred_q[w][lane]; a.x+=t.x; a.y+=t.y; a.z+=t.z; a.w+=t.w; }
    ((float4*)(p + 64))[lane] = a;
  }
}

// ======== k_red: deterministic partials reduce -> BN scale/shift (1 block) ========
__global__ __launch_bounds__(256) void k_red(const float* __restrict__ part, int nblk,
    const float* __restrict__ gamma, const float* __restrict__ beta,
    float* __restrict__ bnc){            // bnc[0..64)=scale, [64..128)=shift
  __shared__ float ssum[4][64], ssq[4][64];
  int tid = threadIdx.x;
  int c = tid & 63, sl = tid >> 6;       // 4 slices over blocks
  float s = 0.f, q = 0.f;
  for (int i = sl; i < nblk; i += 4){    // fixed order -> bitwise deterministic
    s += part[i*128 + c];
    q += part[i*128 + 64 + c];
  }
  ssum[sl][c] = s; ssq[sl][c] = q;
  __syncthreads();
  if (tid < 64){
    float S = ssum[0][tid]+ssum[1][tid]+ssum[2][tid]+ssum[3][tid];
    float Q = ssq[0][tid]+ssq[1][tid]+ssq[2][tid]+ssq[3][tid];
    float mu = S*(1.f/BN), var = Q*(1.f/BN) - mu*mu;
    float sc = gamma[tid]/sqrtf(var + 1e-5f);
    bnc[tid] = sc; bnc[64+tid] = beta[tid] - mu*sc;
  }
}

// ================= k3: bn1 + relu + *embed (recomputed) + per-block BN2 partials =========
__global__ __launch_bounds__(256) void k3(const unsigned short* __restrict__ agg,
    const float* __restrict__ embed, const float* __restrict__ bnc,
    float* __restrict__ part2){
  __shared__ float4 sred_s[4][16], sred_q[4][16];
  int tid = threadIdx.x;
  int gt = blockIdx.x*256 + tid;
  int c = gt & 15, r0 = gt >> 4;               // 4096-row stride keeps node const
  int wv = tid >> 6, lane = tid & 63;
  float4 sc1 = ((const float4*)bnc)[c], sh1 = ((const float4*)(bnc+64))[c];
  float4 e4 = ((const float4*)embed)[(r0 & (Nn-1))*16 + c];
  float4 s4 = {0,0,0,0}, q4 = {0,0,0,0};
  const ushort4* a4 = (const ushort4*)agg;
  for (int r = r0; r < BN; r += 4096){
    float4 v = unpack4(a4[r*16 + c]);
    v.x = fmaxf(v.x*sc1.x+sh1.x, 0.f)*e4.x;
    v.y = fmaxf(v.y*sc1.y+sh1.y, 0.f)*e4.y;
    v.z = fmaxf(v.z*sc1.z+sh1.z, 0.f)*e4.z;
    v.w = fmaxf(v.w*sc1.w+sh1.w, 0.f)*e4.w;
    s4.x += v.x; s4.y += v.y; s4.z += v.z; s4.w += v.w;
    q4.x += v.x*v.x; q4.y += v.y*v.y; q4.z += v.z*v.z; q4.w += v.w*v.w;
  }
  #pragma unroll
  for (int o = 16; o <= 32; o <<= 1){
    s4.x += __shfl_xor(s4.x,o,64); s4.y += __shfl_xor(s4.y,o,64);
    s4.z += __shfl_xor(s4.z,o,64); s4.w += __shfl_xor(s4.w,o,64);
    q4.x += __shfl_xor(q4.x,o,64); q4.y += __shfl_xor(q4.y,o,64);
    q4.z += __shfl_xor(q4.z,o,64); q4.w += __shfl_xor(q4.w,o,64);
  }
  if (lane < 16){ sred_s[wv][lane] = s4; sred_q[wv][lane] = q4; }
  __syncthreads();
  float* p = part2 + blockIdx.x*128;
  if (wv == 0 && lane < 16){
    float4 a = sred_s[0][lane];
    #pragma unroll
    for (int w = 1; w < 4; w++){ float4 t = sred_s[w][lane]; a.x+=t.x; a.y+=t.y; a.z+=t.z; a.w+=t.w; }
    ((float4*)p)[lane] = a;
  }
  if (wv == 1 && lane < 16){
    float4 a = sred_q[0][lane];
    #pragma unroll
    for (int w = 1; w < 4; w++){ float4 t = sred_q[w][lane]; a.x+=t.x; a.y+=t.y; a.z+=t.z; a.w+=t.w; }
    ((float4*)(p + 64))[lane] = a;
  }
}

// ================= k4: bn1+relu+*embed, bn2+relu, Linear(D,1) head =================
__global__ __launch_bounds__(256) void k4(const unsigned short* __restrict__ agg,
    const float* __restrict__ embed, const float* __restrict__ bnc,
    const float* __restrict__ outW, const float* __restrict__ outb,
    float* __restrict__ out){
  int tid = threadIdx.x;
  int gt = blockIdx.x*256 + tid;
  int c = gt & 15, r0 = gt >> 4;
  float4 sc1 = ((const float4*)bnc)[c],       sh1 = ((const float4*)(bnc+64))[c];
  float4 sc2 = ((const float4*)(bnc+128))[c], sh2 = ((const float4*)(bnc+192))[c];
  float4 ow  = ((const float4*)outW)[c];
  float ob = outb[0];
  float4 e4 = ((const float4*)embed)[(r0 & (Nn-1))*16 + c];
  const ushort4* a4 = (const ushort4*)agg;
  for (int r = r0; r < BN; r += 4096){
    float4 v = unpack4(a4[r*16 + c]);
    v.x = fmaxf(v.x*sc1.x+sh1.x, 0.f)*e4.x;
    v.y = fmaxf(v.y*sc1.y+sh1.y, 0.f)*e4.y;
    v.z = fmaxf(v.z*sc1.z+sh1.z, 0.f)*e4.z;
    v.w = fmaxf(v.w*sc1.w+sh1.w, 0.f)*e4.w;
    float t = fmaxf(v.x*sc2.x+sh2.x, 0.f)*ow.x
            + fmaxf(v.y*sc2.y+sh2.y, 0.f)*ow.y
            + fmaxf(v.z*sc2.z+sh2.z, 0.f)*ow.z
            + fmaxf(v.w*sc2.w+sh2.w, 0.f)*ow.w;
    #pragma unroll
    for (int o = 1; o < 16; o <<= 1) t += __shfl_xor(t, o, 64);
    if (c == 0) out[r] = t + ob;
  }
}

extern "C" void kernel_launch(void* const* d_in, const int* in_sizes, int n_in,
                              void* d_out, int out_size, void* d_ws, size_t ws_size,
                              hipStream_t stream){
  const float* data  = (const float*)d_in[0];
  // d_in[1] = org_edge_index — unused by the reference computation
  const float* embed = (const float*)d_in[2];
  const float* W_lin = (const float*)d_in[3];
  const float* att_i = (const float*)d_in[4];
  const float* att_j = (const float*)d_in[5];
  const float* aem_i = (const float*)d_in[6];
  const float* aem_j = (const float*)d_in[7];
  const float* bias  = (const float*)d_in[8];
  const float* g1    = (const float*)d_in[9];
  const float* b1    = (const float*)d_in[10];
  const float* g2    = (const float*)d_in[11];
  const float* b2    = (const float*)d_in[12];
  const float* outW  = (const float*)d_in[13];
  const float* outb  = (const float*)d_in[14];
  float* out = (float*)d_out;

  float* ws = (float*)d_ws;
  unsigned short* g   = (unsigned short*)ws;              // 8 MB bf16
  unsigned short* agg = (unsigned short*)(ws + 2097152);  // 8 MB bf16
  float* s_i   = ws + 4194304;             // 65,536 f32
  float* s_j   = s_i + 65536;              // 65,536 f32
  int*   topk  = (int*)(s_j + 65536);      // 10,240 int
  float* part1 = (float*)(topk + Nn*Kk);   // 512*128 f32
  float* part2 = part1 + 512*128;          // 256*128 f32
  float* bnc   = part2 + 256*128;          // 256 f32: sc1,sh1,sc2,sh2

  k_topk<<<128, 256, 0, stream>>>(embed, topk);
  k_lin <<<1024, 256, 0, stream>>>(data, W_lin, embed, att_i, att_j, aem_i, aem_j,
                                   g, s_i, s_j);
  k2    <<<512, 256, 0, stream>>>(g, s_i, s_j, topk, bias, agg, part1);
  k_red <<<1, 256, 0, stream>>>(part1, 512, g1, b1, bnc);
  k3    <<<256, 256, 0, stream>>>(agg, embed, bnc, part2);
  k_red <<<1, 256, 0, stream>>>(part2, 256, g2, b2, bnc + 128);
  k4    <<<256, 256, 0, stream>>>(agg, embed, bnc, outW, outb, out);
}

// Round 8
// 221.529 us; speedup vs baseline: 2.5521x; 1.1341x over previous
//
#include <hip/hip_runtime.h>
#include <math.h>

#define Bsz 128
#define Nn  512
#define Fd  64
#define Dd  64
#define Kk  20
#define BN  (Bsz*Nn)   // 65536

__device__ __forceinline__ float leaky(float v){ return (v >= 0.f) ? v : 0.2f*v; }

// bf16 helpers (RNE)
__device__ __forceinline__ unsigned short f2bf(float f){
  unsigned u = __float_as_uint(f);
  return (unsigned short)((u + 0x7FFFu + ((u >> 16) & 1u)) >> 16);
}
__device__ __forceinline__ float bf2f(unsigned short h){
  return __uint_as_float(((unsigned)h) << 16);
}
__device__ __forceinline__ ushort4 pack4(float4 v){
  ushort4 r; r.x = f2bf(v.x); r.y = f2bf(v.y); r.z = f2bf(v.z); r.w = f2bf(v.w);
  return r;
}
__device__ __forceinline__ float4 unpack4(ushort4 v){
  float4 r; r.x = bf2f(v.x); r.y = bf2f(v.y); r.z = bf2f(v.z); r.w = bf2f(v.w);
  return r;
}

// reduce over lanes 0..31 only (lanes 32-63 hold identity values)
__device__ __forceinline__ float wave_max32(float v){
  #pragma unroll
  for (int o = 16; o; o >>= 1) v = fmaxf(v, __shfl_xor(v, o, 64));
  return v;
}
__device__ __forceinline__ float wave_sum32(float v){
  #pragma unroll
  for (int o = 16; o; o >>= 1) v += __shfl_xor(v, o, 64);
  return v;
}

// ================= kA: blocks [0,128) topk FIRST, [128,1152) GEMM =================
// topk blocks lead the dispatch order so they overlap the GEMM instead of
// trailing it (R4 put them last: 68 us fused; theory = serialized tail).
// NOTE (R5 lesson): no min-waves launch_bounds floor, no full unroll of the qk
// loop — (256,4) capped VGPR at 64 and spilled accumulators (1 GB scratch traffic).
__global__ __launch_bounds__(256) void kA(const float* __restrict__ x,
    const float* __restrict__ W, const float* __restrict__ embed,
    const float* __restrict__ att_i, const float* __restrict__ att_j,
    const float* __restrict__ aem_i, const float* __restrict__ aem_j,
    unsigned short* __restrict__ g, float* __restrict__ s_i, float* __restrict__ s_j,
    int* __restrict__ topk){
  __shared__ __align__(16) float4 sW[Fd*16];          // 16 KB (GEMM path)
  __shared__ __align__(16) float4 sai[16], saj[16], semi[16], semj[16];
  __shared__ __align__(16) float rnorm[Nn];           // topk path
  __shared__ __align__(16) float se[256];
  int tid = threadIdx.x, b = blockIdx.x;

  if (b < 128){
    // ---------- topk: 4 waves, one row each ----------
    int bb = b;
    for (int r = tid; r < Nn; r += 256){
      const float4* er = (const float4*)(embed + r*Dd);
      float ss = 0.f;
      #pragma unroll
      for (int q = 0; q < 16; q++){
        float4 e4 = er[q];
        ss += e4.x*e4.x + e4.y*e4.y + e4.z*e4.z + e4.w*e4.w;
      }
      rnorm[r] = 1.f/(sqrtf(ss) + 1e-12f);
    }
    se[tid] = embed[bb*256 + tid];       // this block's 4 query rows
    __syncthreads();
    int wv = tid >> 6, lane = tid & 63;
    int row = bb*4 + wv;
    const float4* sev = (const float4*)(se + wv*64);
    float av[8];
    #pragma unroll
    for (int rep = 0; rep < 8; rep++){
      int c = rep*64 + lane;
      const float4* ej = (const float4*)(embed + c*Dd);
      float s0 = 0.f;
      #pragma unroll
      for (int q = 0; q < 16; q++){
        float4 a = ej[q], b4 = sev[q];
        s0 += a.x*b4.x + a.y*b4.y + a.z*b4.z + a.w*b4.w;
      }
      av[rep] = s0 * rnorm[c];           // query-row norm is argmax-invariant
    }
    #pragma unroll 1
    for (int t = 0; t < Kk; t++){
      float bv = av[0]; int br = 0;
      #pragma unroll
      for (int rep = 1; rep < 8; rep++)
        if (av[rep] > bv){ bv = av[rep]; br = rep; }   // strict > = lowest c per lane
      int ci = br*64 + lane;
      #pragma unroll
      for (int o = 32; o; o >>= 1){
        float ov = __shfl_xor(bv, o, 64);
        int   oi = __shfl_xor(ci, o, 64);
        if (ov > bv || (ov == bv && oi < ci)){ bv = ov; ci = oi; }
      }
      if (lane == 0) topk[row*Kk + t] = ci;
      int wr = ci >> 6;
      if ((ci & 63) == lane){
        #pragma unroll
        for (int rep = 0; rep < 8; rep++)
          if (rep == wr) av[rep] = -INFINITY;
      }
    }
  } else {
    // ---------- GEMM: g = x@W (bf16) + attention scores ----------
    int bG = b - 128;
    const float4* W4 = (const float4*)W;
    #pragma unroll
    for (int t = 0; t < 4; t++) sW[tid + 256*t] = W4[tid + 256*t];
    if (tid < 16){
      sai[tid]  = ((const float4*)att_i)[tid];
      saj[tid]  = ((const float4*)att_j)[tid];
      semi[tid] = ((const float4*)aem_i)[tid];
      semj[tid] = ((const float4*)aem_j)[tid];
    }
    __syncthreads();
    int rowgrp = tid >> 4, cg = tid & 15;
    int row0 = bG*64 + rowgrp*4;
    float4 acc0={0,0,0,0}, acc1={0,0,0,0}, acc2={0,0,0,0}, acc3={0,0,0,0};
    const float4* xr0 = (const float4*)(x + (row0+0)*Fd);
    const float4* xr1 = (const float4*)(x + (row0+1)*Fd);
    const float4* xr2 = (const float4*)(x + (row0+2)*Fd);
    const float4* xr3 = (const float4*)(x + (row0+3)*Fd);
    for (int qk = 0; qk < 16; qk++){
      float4 x0 = xr0[qk], x1 = xr1[qk], x2 = xr2[qk], x3 = xr3[qk];
      float xs0[4] = {x0.x,x0.y,x0.z,x0.w};
      float xs1[4] = {x1.x,x1.y,x1.z,x1.w};
      float xs2[4] = {x2.x,x2.y,x2.z,x2.w};
      float xs3[4] = {x3.x,x3.y,x3.z,x3.w};
      #pragma unroll
      for (int s = 0; s < 4; s++){
        float4 w4 = sW[(4*qk + s)*16 + cg];
        acc0.x += xs0[s]*w4.x; acc0.y += xs0[s]*w4.y; acc0.z += xs0[s]*w4.z; acc0.w += xs0[s]*w4.w;
        acc1.x += xs1[s]*w4.x; acc1.y += xs1[s]*w4.y; acc1.z += xs1[s]*w4.z; acc1.w += xs1[s]*w4.w;
        acc2.x += xs2[s]*w4.x; acc2.y += xs2[s]*w4.y; acc2.z += xs2[s]*w4.z; acc2.w += xs2[s]*w4.w;
        acc3.x += xs3[s]*w4.x; acc3.y += xs3[s]*w4.y; acc3.z += xs3[s]*w4.z; acc3.w += xs3[s]*w4.w;
      }
    }
    float4 ai = sai[cg], aj = saj[cg], emi = semi[cg], emj = semj[cg];
    float4 avv[4] = {acc0, acc1, acc2, acc3};
    #pragma unroll
    for (int r = 0; r < 4; r++){
      int row = row0 + r;
      int node = row & (Nn-1);
      float4 a4 = avv[r];
      float4 e4 = ((const float4*)embed)[node*16 + cg];
      float si = a4.x*ai.x + a4.y*ai.y + a4.z*ai.z + a4.w*ai.w
               + e4.x*emi.x + e4.y*emi.y + e4.z*emi.z + e4.w*emi.w;
      float sj = a4.x*aj.x + a4.y*aj.y + a4.z*aj.z + a4.w*aj.w
               + e4.x*emj.x + e4.y*emj.y + e4.z*emj.z + e4.w*emj.w;
      #pragma unroll
      for (int o = 1; o < 16; o <<= 1){
        si += __shfl_xor(si, o, 64);
        sj += __shfl_xor(sj, o, 64);
      }
      if (cg == 0){ s_i[row] = si; s_j[row] = sj; }
      ((ushort4*)g)[row*16 + cg] = pack4(a4);     // bf16 g
    }
  }
}

// ================= k2: softmax + gather-aggregate (bf16) + per-block BN1 partials ==========
// NO atomics / NO memset: each block owns part1[bid*128 .. +128) — deterministic
// under graph replay (round 6 post-timing tripwire traced to memset+atomic stats).
__global__ __launch_bounds__(256) void k2(const unsigned short* __restrict__ g,
    const float* __restrict__ s_i, const float* __restrict__ s_j,
    const int* __restrict__ topk, const float* __restrict__ bias,
    unsigned short* __restrict__ agg, float* __restrict__ part1){
  __shared__ float  swt[4][4][24];
  __shared__ int    sji[4][4][24];
  __shared__ float4 sred_s[4][16], sred_q[4][16];
  __shared__ float4 sbias[16];
  int tid = threadIdx.x, wv = tid >> 6, lane = tid & 63;
  if (tid < 16) sbias[tid] = ((const float4*)bias)[tid];
  __syncthreads();
  // bid%8 preserved -> each batch's g-slab stays on one XCD's L2
  int bid = blockIdx.x;
  int xcd = bid & 7, q = bid >> 3;             // q 0..63
  int batch = xcd*16 + (q & 15);
  int quarter = q >> 4;                        // 0..3
  int base = batch*Nn;
  int node0 = quarter*128 + wv*32;
  const ushort4* g4 = (const ushort4*)g;
  int h = lane >> 4, c = lane & 15;
  float4 s4 = {0,0,0,0}, q4 = {0,0,0,0};
  #pragma unroll 1
  for (int gI = 0; gI < 8; gI++){
    #pragma unroll
    for (int h4 = 0; h4 < 4; h4++){
      int node = node0 + gI*4 + h4;
      int dest = base + node;
      float si_d = s_i[dest];
      float lg = -INFINITY; int j = node;
      if (lane < Kk){
        j = topk[node*Kk + lane];
        if (j != node) lg = leaky(si_d + s_j[base + j]);  // self in topk masked
      } else if (lane == Kk){
        lg = leaky(si_d + s_j[dest]);                     // appended self loop
      }
      // lanes 32-63 hold identity values; only lanes<24 consume the result
      float m  = wave_max32(lg);
      float e_ = (lane <= Kk) ? __expf(lg - m) : 0.f;     // one exp per edge lane
      float denom = wave_sum32(e_);
      if (lane < 24){
        swt[wv][h4][lane] = (lane <= Kk) ? e_/denom : 0.f;
        sji[wv][h4][lane] = j;
      }
    }
    float la[24]; int ja[24];                 // wave-synchronous LDS readback
    const float4* lv = (const float4*)swt[wv][h];
    const int4*   jv = (const int4*)sji[wv][h];
    #pragma unroll
    for (int qq = 0; qq < 6; qq++){
      float4 f = lv[qq]; la[4*qq]=f.x; la[4*qq+1]=f.y; la[4*qq+2]=f.z; la[4*qq+3]=f.w;
      int4  ii = jv[qq]; ja[4*qq]=ii.x; ja[4*qq+1]=ii.y; ja[4*qq+2]=ii.z; ja[4*qq+3]=ii.w;
    }
    float4 acc = sbias[c];
    #pragma unroll
    for (int e = 0; e <= Kk; e++){
      float4 gv = unpack4(g4[(base + ja[e])*16 + c]);  // bf16 gather, 4 dests/round
      acc.x += la[e]*gv.x; acc.y += la[e]*gv.y; acc.z += la[e]*gv.z; acc.w += la[e]*gv.w;
    }
    int dest = base + node0 + gI*4 + h;
    ((ushort4*)agg)[dest*16 + c] = pack4(acc);         // bf16 agg
    s4.x += acc.x; s4.y += acc.y; s4.z += acc.z; s4.w += acc.w;   // fp32 stats
    q4.x += acc.x*acc.x; q4.y += acc.y*acc.y; q4.z += acc.z*acc.z; q4.w += acc.w*acc.w;
  }
  #pragma unroll
  for (int o = 16; o <= 32; o <<= 1){
    s4.x += __shfl_xor(s4.x,o,64); s4.y += __shfl_xor(s4.y,o,64);
    s4.z += __shfl_xor(s4.z,o,64); s4.w += __shfl_xor(s4.w,o,64);
    q4.x += __shfl_xor(q4.x,o,64); q4.y += __shfl_xor(q4.y,o,64);
    q4.z += __shfl_xor(q4.z,o,64); q4.w += __shfl_xor(q4.w,o,64);
  }
  if (lane < 16){ sred_s[wv][lane] = s4; sred_q[wv][lane] = q4; }
  __syncthreads();
  float* p = part1 + bid*128;
  if (wv == 0 && lane < 16){
    float4 a = sred_s[0][lane];
    #pragma unroll
    for (int w = 1; w < 4; w++){ float4 t = sred_s[w][lane]; a.x+=t.x; a.y+=t.y; a.z+=t.z; a.w+=t.w; }
    ((float4*)p)[lane] = a;
  }
  if (wv == 1 && lane < 16){
    float4 a = sred_q[0][lane];
    #pragma unroll
    for (int w = 1; w < 4; w++){ float4 t = sred_q[w][lane]; a.x+=t.x; a.y+=t.y; a.z+=t.z; a.w+=t.w; }
    ((float4*)(p + 64))[lane] = a;
  }
}

// ===== k3: inline part1 reduce -> bn1 consts; recompute h2; per-block BN2 partials =====
// Every block redundantly reduces part1 in a FIXED order (bitwise identical);
// block 0 publishes bnc1 for k4. No atomics, no memset.
__global__ __launch_bounds__(256) void k3(const unsigned short* __restrict__ agg,
    const float* __restrict__ embed, const float* __restrict__ part1,
    const float* __restrict__ bn1g, const float* __restrict__ bn1b,
    float* __restrict__ bnc, float* __restrict__ part2){
  __shared__ float sred[2][128];
  __shared__ float ssc[64], ssh[64];
  __shared__ float4 sred_s[4][16], sred_q[4][16];
  int tid = threadIdx.x;
  {
    int cc = tid & 127, sl = tid >> 7;         // 2 slices x 128 channels
    float s = 0.f;
    for (int i = sl*256; i < sl*256 + 256; i++) s += part1[i*128 + cc];
    sred[sl][cc] = s;
    __syncthreads();
    if (tid < 64){
      float S = sred[0][tid] + sred[1][tid];
      float Q = sred[0][64+tid] + sred[1][64+tid];
      float mu = S*(1.f/BN), var = Q*(1.f/BN) - mu*mu;
      float sc = bn1g[tid]/sqrtf(var + 1e-5f);
      float sh = bn1b[tid] - mu*sc;
      ssc[tid] = sc; ssh[tid] = sh;
      if (blockIdx.x == 0){ bnc[tid] = sc; bnc[64+tid] = sh; }
    }
    __syncthreads();
  }
  int gt = blockIdx.x*256 + tid;
  int c = gt & 15, r0 = gt >> 4;               // 4096-row stride keeps node const
  int wv = tid >> 6, lane = tid & 63;
  float4 sc1 = ((const float4*)ssc)[c], sh1 = ((const float4*)ssh)[c];
  float4 e4 = ((const float4*)embed)[(r0 & (Nn-1))*16 + c];
  float4 s4 = {0,0,0,0}, q4 = {0,0,0,0};
  const ushort4* a4 = (const ushort4*)agg;
  for (int r = r0; r < BN; r += 4096){
    float4 v = unpack4(a4[r*16 + c]);
    v.x = fmaxf(v.x*sc1.x+sh1.x, 0.f)*e4.x;
    v.y = fmaxf(v.y*sc1.y+sh1.y, 0.f)*e4.y;
    v.z = fmaxf(v.z*sc1.z+sh1.z, 0.f)*e4.z;
    v.w = fmaxf(v.w*sc1.w+sh1.w, 0.f)*e4.w;
    s4.x += v.x; s4.y += v.y; s4.z += v.z; s4.w += v.w;
    q4.x += v.x*v.x; q4.y += v.y*v.y; q4.z += v.z*v.z; q4.w += v.w*v.w;
  }
  #pragma unroll
  for (int o = 16; o <= 32; o <<= 1){
    s4.x += __shfl_xor(s4.x,o,64); s4.y += __shfl_xor(s4.y,o,64);
    s4.z += __shfl_xor(s4.z,o,64); s4.w += __shfl_xor(s4.w,o,64);
    q4.x += __shfl_xor(q4.x,o,64); q4.y += __shfl_xor(q4.y,o,64);
    q4.z += __shfl_xor(q4.z,o,64); q4.w += __shfl_xor(q4.w,o,64);
  }
  if (lane < 16){ sred_s[wv][lane] = s4; sred_q[wv][lane] = q4; }
  __syncthreads();
  float* p = part2 + blockIdx.x*128;
  if (wv == 0 && lane < 16){
    float4 a = sred_s[0][lane];
    #pragma unroll
    for (int w = 1; w < 4; w++){ float4 t = sred_s[w][lane]; a.x+=t.x; a.y+=t.y; a.z+=t.z; a.w+=t.w; }
    ((float4*)p)[lane] = a;
  }
  if (wv == 1 && lane < 16){
    float4 a = sred_q[0][lane];
    #pragma unroll
    for (int w = 1; w < 4; w++){ float4 t = sred_q[w][lane]; a.x+=t.x; a.y+=t.y; a.z+=t.z; a.w+=t.w; }
    ((float4*)(p + 64))[lane] = a;
  }
}

// ===== k4: inline part2 reduce -> bn2 consts; bn1(bnc)+relu+*embed, bn2+relu, head =====
__global__ __launch_bounds__(256) void k4(const unsigned short* __restrict__ agg,
    const float* __restrict__ embed, const float* __restrict__ part2,
    const float* __restrict__ bnc, const float* __restrict__ bn2g,
    const float* __restrict__ bn2b, const float* __restrict__ outW,
    const float* __restrict__ outb, float* __restrict__ out){
  __shared__ float sred[2][128];
  __shared__ float ssc2[64], ssh2[64];
  int tid = threadIdx.x;
  {
    int cc = tid & 127, sl = tid >> 7;         // 2 slices x 128 channels
    float s = 0.f;
    for (int i = sl*128; i < sl*128 + 128; i++) s += part2[i*128 + cc];
    sred[sl][cc] = s;
    __syncthreads();
    if (tid < 64){
      float S = sred[0][tid] + sred[1][tid];
      float Q = sred[0][64+tid] + sred[1][64+tid];
      float mu = S*(1.f/BN), var = Q*(1.f/BN) - mu*mu;
      float sc = bn2g[tid]/sqrtf(var + 1e-5f);
      ssc2[tid] = sc; ssh2[tid] = bn2b[tid] - mu*sc;
    }
    __syncthreads();
  }
  int gt = blockIdx.x*256 + tid;
  int c = gt & 15, r0 = gt >> 4;
  float4 sc1 = ((const float4*)bnc)[c],  sh1 = ((const float4*)(bnc+64))[c];
  float4 sc2 = ((const float4*)ssc2)[c], sh2 = ((const float4*)ssh2)[c];
  float4 ow  = ((const float4*)outW)[c];
  float ob = outb[0];
  float4 e4 = ((const float4*)embed)[(r0 & (Nn-1))*16 + c];
  const ushort4* a4 = (const ushort4*)agg;
  for (int r = r0; r < BN; r += 4096){
    float4 v = unpack4(a4[r*16 + c]);
    v.x = fmaxf(v.x*sc1.x+sh1.x, 0.f)*e4.x;
    v.y = fmaxf(v.y*sc1.y+sh1.y, 0.f)*e4.y;
    v.z = fmaxf(v.z*sc1.z+sh1.z, 0.f)*e4.z;
    v.w = fmaxf(v.w*sc1.w+sh1.w, 0.f)*e4.w;
    float t = fmaxf(v.x*sc2.x+sh2.x, 0.f)*ow.x
            + fmaxf(v.y*sc2.y+sh2.y, 0.f)*ow.y
            + fmaxf(v.z*sc2.z+sh2.z, 0.f)*ow.z
            + fmaxf(v.w*sc2.w+sh2.w, 0.f)*ow.w;
    #pragma unroll
    for (int o = 1; o < 16; o <<= 1) t += __shfl_xor(t, o, 64);
    if (c == 0) out[r] = t + ob;
  }
}

extern "C" void kernel_launch(void* const* d_in, const int* in_sizes, int n_in,
                              void* d_out, int out_size, void* d_ws, size_t ws_size,
                              hipStream_t stream){
  const float* data  = (const float*)d_in[0];
  // d_in[1] = org_edge_index — unused by the reference computation
  const float* embed = (const float*)d_in[2];
  const float* W_lin = (const float*)d_in[3];
  const float* att_i = (const float*)d_in[4];
  const float* att_j = (const float*)d_in[5];
  const float* aem_i = (const float*)d_in[6];
  const float* aem_j = (const float*)d_in[7];
  const float* bias  = (const float*)d_in[8];
  const float* g1    = (const float*)d_in[9];
  const float* b1    = (const float*)d_in[10];
  const float* g2    = (const float*)d_in[11];
  const float* b2    = (const float*)d_in[12];
  const float* outW  = (const float*)d_in[13];
  const float* outb  = (const float*)d_in[14];
  float* out = (float*)d_out;

  float* ws = (float*)d_ws;
  unsigned short* g   = (unsigned short*)ws;              // 8 MB bf16
  unsigned short* agg = (unsigned short*)(ws + 2097152);  // 8 MB bf16
  float* s_i   = ws + 4194304;             // 65,536 f32
  float* s_j   = s_i + 65536;              // 65,536 f32
  int*   topk  = (int*)(s_j + 65536);      // 10,240 int
  float* part1 = (float*)(topk + Nn*Kk);   // 512*128 f32
  float* part2 = part1 + 512*128;          // 256*128 f32
  float* bnc   = part2 + 256*128;          // 128 f32: sc1, sh1

  kA<<<1152, 256, 0, stream>>>(data, W_lin, embed, att_i, att_j, aem_i, aem_j,
                               g, s_i, s_j, topk);
  k2<<<512, 256, 0, stream>>>(g, s_i, s_j, topk, bias, agg, part1);
  k3<<<256, 256, 0, stream>>>(agg, embed, part1, g1, b1, bnc, part2);
  k4<<<256, 256, 0, stream>>>(agg, embed, part2, bnc, g2, b2, outW, outb, out);
}